// Round 1
// baseline (731.728 us; speedup 1.0000x reference)
//
#include <hip/hip_runtime.h>

// RotarySelfAttention on MI355X (gfx950).
// Round 3: k_attn sync-structure rewrite (T3/T4 counted-wait style).
//   - raw s_barrier + lgkmcnt(0)-only drains (no vmcnt(0) at barriers):
//     K prefetch survives across the barrier; V loads span QK+softmax.
//   - V loads issued first; softmax moved before V-dependent sVT staging.
//   - XOR swizzle (col ^= ((row>>2)&7)<<3) on sVT and sP kills the 8-way /
//     4-way write bank conflicts (reads stay 16B-aligned).
//   - s_setprio(1) around QK and PV MFMA clusters (T5).
// k_qkv / k_oproj / k_reduce / preprocessing unchanged from round 2.

typedef unsigned short u16;
typedef unsigned int   u32;
typedef float  f32x4  __attribute__((ext_vector_type(4)));
typedef __bf16 bf16x8 __attribute__((ext_vector_type(8)));

#define DEV static __device__ __forceinline__

constexpr int NP = 3584;

DEV u16 bf16rn(float f){
  u32 u = __float_as_uint(f);
  return (u16)((u + 0x7fffu + ((u >> 16) & 1u)) >> 16);
}
DEV float bf2f(u16 h){ return __uint_as_float((u32)h << 16); }
DEV void split2(float f, u16 &h, u16 &l){ h = bf16rn(f); l = bf16rn(f - bf2f(h)); }

DEV f32x4 mfma16(bf16x8 a, bf16x8 b, f32x4 c){
  return __builtin_amdgcn_mfma_f32_16x16x32_bf16(a, b, c, 0, 0, 0);
}

// barrier with LDS-only drain: ds_writes visible, VMEM loads stay in flight.
DEV void bar_nodrain(){
  asm volatile("s_waitcnt lgkmcnt(0)" ::: "memory");
  __builtin_amdgcn_s_barrier();
  __builtin_amdgcn_sched_barrier(0);   // rule-18 fence: nothing hoists above
}

// bank-spread swizzle for row-major u16 tiles with 72-element stride
DEV int swz(int row, int col){ return col ^ (((row >> 2) & 7) << 3); }

// ---------------- split x into hi/lo bf16 ----------------
__global__ __launch_bounds__(256) void k_split_x(const float* __restrict__ x,
                                                 u16* __restrict__ xh, u16* __restrict__ xl){
  int i = blockIdx.x * 256 + threadIdx.x;
  float4 v = ((const float4*)x)[i];
  u16 h0,l0,h1,l1,h2,l2,h3,l3;
  split2(v.x,h0,l0); split2(v.y,h1,l1); split2(v.z,h2,l2); split2(v.w,h3,l3);
  ushort4 hv; hv.x=h0; hv.y=h1; hv.z=h2; hv.w=h3;
  ushort4 lv; lv.x=l0; lv.y=l1; lv.z=l2; lv.w=l3;
  ((ushort4*)xh)[i] = hv; ((ushort4*)xl)[i] = lv;
}

// ------------- transpose + split weights: Wt[n][k] = W[k][n] -------------
__global__ __launch_bounds__(256) void k_wsplit(const float* __restrict__ w0, const float* __restrict__ w1,
                                                const float* __restrict__ w2, const float* __restrict__ w3,
                                                u16* __restrict__ Wth, u16* __restrict__ Wtl){
  __shared__ float tl[64][65];
  int z = blockIdx.z;
  const float* W = (z==0) ? w0 : (z==1) ? w1 : (z==2) ? w2 : w3;
  u16* oh = Wth + (size_t)z * (1024*1024);
  u16* ol = Wtl + (size_t)z * (1024*1024);
  int n0 = blockIdx.x*64, k0 = blockIdx.y*64;
  int tid = threadIdx.x;
  #pragma unroll
  for (int i=0;i<16;++i){
    int idx = i*256 + tid; int rr = idx >> 6, cc = idx & 63;
    tl[rr][cc] = W[(size_t)(k0+rr)*1024 + n0 + cc];
  }
  __syncthreads();
  #pragma unroll
  for (int i=0;i<16;++i){
    int idx = i*256 + tid; int rr = idx >> 6, cc = idx & 63;
    u16 h,l; split2(tl[cc][rr], h, l);
    size_t o = (size_t)(n0+rr)*1024 + k0 + cc;
    oh[o] = h; ol[o] = l;
  }
}

// ---------------- QKV projection GEMM + bias + RoPE + mask ----------------
__global__ __launch_bounds__(256) void k_qkv(
    const u16* __restrict__ xh, const u16* __restrict__ xl,
    const u16* __restrict__ Wth, const u16* __restrict__ Wtl,
    const float* __restrict__ bq, const float* __restrict__ bk, const float* __restrict__ bv,
    const float* __restrict__ rcos, const float* __restrict__ rsin,
    const int* __restrict__ cnts,
    u16* __restrict__ qh, u16* __restrict__ ql,
    u16* __restrict__ kh, u16* __restrict__ vh)
{
  int zi = blockIdx.z;
  int n0 = blockIdx.x * 128, m0 = blockIdx.y * 128;
  int b = m0 >> 9, t0 = m0 & 511;
  int cnt = cnts[b];
  if (t0 >= cnt) return;
  const u16* Bh = Wth + (size_t)zi * (1024*1024);
  const u16* Bl = Wtl + (size_t)zi * (1024*1024);
  const float* bias = (zi==0) ? bq : (zi==1) ? bk : bv;
  u16* oh = (zi==0) ? qh : (zi==1) ? kh : vh;
  u16* ol = ql;                       // only written when zi==0

  __shared__ u16 sA[2][128*40];
  __shared__ u16 sB[2][128*40];

  int tid = threadIdx.x, lane = tid & 63, wid = tid >> 6;
  int r = lane & 15, quad = lane >> 4;
  int wm = (wid >> 1) * 64, wn = (wid & 1) * 64;

  const f32x4 fz = {0.f,0.f,0.f,0.f};
  f32x4 acc[4][4];
  #pragma unroll
  for (int i=0;i<4;++i){
    #pragma unroll
    for (int j=0;j<4;++j) acc[i][j] = fz;
  }

  int srow = tid >> 2, sc8 = (tid & 3) * 8;

  for (int kt = 0; kt < 32; ++kt){
    int kb = kt * 32;
    __syncthreads();
    {
      size_t ga  = (size_t)(m0 + srow) * 1024 + kb + sc8;
      size_t gb  = (size_t)(n0 + srow) * 1024 + kb + sc8;
      int lo = srow*40 + sc8, lo2 = lo + 64*40;
      *(uint4*)&sA[0][lo]  = *(const uint4*)&xh[ga];
      *(uint4*)&sA[1][lo]  = *(const uint4*)&xl[ga];
      *(uint4*)&sB[0][lo]  = *(const uint4*)&Bh[gb];
      *(uint4*)&sB[1][lo]  = *(const uint4*)&Bl[gb];
      *(uint4*)&sA[0][lo2] = *(const uint4*)&xh[ga + 64*1024];
      *(uint4*)&sA[1][lo2] = *(const uint4*)&xl[ga + 64*1024];
      *(uint4*)&sB[0][lo2] = *(const uint4*)&Bh[gb + 64*1024];
      *(uint4*)&sB[1][lo2] = *(const uint4*)&Bl[gb + 64*1024];
    }
    __syncthreads();
    bf16x8 ah[4], al[4], bh8[4], bl8[4];
    #pragma unroll
    for (int mf=0; mf<4; ++mf){
      int off = (wm + mf*16 + r)*40 + quad*8;
      ah[mf] = *(const bf16x8*)&sA[0][off];
      al[mf] = *(const bf16x8*)&sA[1][off];
    }
    #pragma unroll
    for (int nf=0; nf<4; ++nf){
      int off = (wn + nf*16 + r)*40 + quad*8;
      bh8[nf] = *(const bf16x8*)&sB[0][off];
      bl8[nf] = *(const bf16x8*)&sB[1][off];
    }
    #pragma unroll
    for (int mf=0; mf<4; ++mf){
      #pragma unroll
      for (int nf=0; nf<4; ++nf){
        acc[mf][nf] = mfma16(ah[mf], bh8[nf], acc[mf][nf]);
        acc[mf][nf] = mfma16(al[mf], bh8[nf], acc[mf][nf]);
        acc[mf][nf] = mfma16(ah[mf], bl8[nf], acc[mf][nf]);
      }
    }
  }

  float vals[4][4][4];
  #pragma unroll
  for (int mf=0;mf<4;++mf){
    #pragma unroll
    for (int nf=0;nf<4;++nf){
      float bb = bias[n0 + wn + nf*16 + r];
      #pragma unroll
      for (int e=0;e<4;++e) vals[mf][nf][e] = acc[mf][nf][e] + bb;
    }
  }
  if (zi < 2){
    #pragma unroll
    for (int mf=0;mf<4;++mf){
      #pragma unroll
      for (int e=0;e<4;++e){
        int t = t0 + wm + mf*16 + quad*4 + e;
        #pragma unroll
        for (int nf=0;nf<2;++nf){
          int d = nf*16 + r;
          float c1 = rcos[t*64 + d],      s1 = rsin[t*64 + d];
          float c2 = rcos[t*64 + d + 32], s2 = rsin[t*64 + d + 32];
          float x1 = vals[mf][nf][e], x2 = vals[mf][nf+2][e];
          vals[mf][nf][e]   = x1*c1 - x2*s1;
          vals[mf][nf+2][e] = x2*c2 + x1*s2;
        }
      }
    }
  }
  #pragma unroll
  for (int mf=0;mf<4;++mf){
    #pragma unroll
    for (int e=0;e<4;++e){
      int t = t0 + wm + mf*16 + quad*4 + e;
      float msk = (t < cnt) ? 1.f : 0.f;
      #pragma unroll
      for (int nf=0;nf<4;++nf){
        int gc = n0 + wn + nf*16 + r;
        int head = gc >> 6, d = gc & 63;
        float v = vals[mf][nf][e] * msk;
        u16 hh, ll; split2(v, hh, ll);
        size_t o = ((size_t)(b*16 + head)*512 + t)*64 + d;
        oh[o] = hh;
        if (zi == 0) ol[o] = ll;
      }
    }
  }
}

// ---------------- flash attention, split-K, fixed-max softmax ----------------
__global__ __launch_bounds__(256,3) void k_attn(
    const u16* __restrict__ qh_, const u16* __restrict__ ql_,
    const u16* __restrict__ knh, const u16* __restrict__ vnh,
    const float* __restrict__ pk, const float* __restrict__ pv,
    const int* __restrict__ plen, const int* __restrict__ cnts,
    int S, float* __restrict__ pl, float* __restrict__ pO)
{
  int qt = blockIdx.x, h = blockIdx.y;
  int zb = blockIdx.z;
  int b = zb / S, s = zb - b * S;
  int cnt = cnts[b];
  int q0 = qt * 128;
  if (q0 >= cnt) return;
  int Lp = min(max(plen[b], 0), NP);
  int TL = Lp + cnt;
  int Ln = max(0, TL - NP);
  int jend = min(((Lp + 63) >> 6) << 6, NP);
  int minTLP = min(TL, NP);
  int Zar = max(0, minTLP - jend);
  int npast = jend >> 6, nnew = (Ln + 63) >> 6;
  int Tt = npast + nnew;
  int qsp = (Tt + S - 1) / S;
  int it0 = s * qsp, it1 = min(Tt, it0 + qsp);
  bool hasZ = (s == 0 && Zar > 0);
  if (it0 >= it1 && !hasZ) return;

  __shared__ u16 sK [64*72];
  __shared__ u16 sVT[64*72];
  __shared__ u16 sP [4*32*72];

  int tid = threadIdx.x, lane = tid & 63, wid = tid >> 6;
  int r = lane & 15, quad = lane >> 4;
  int wm0 = wid * 32;

  bf16x8 Qh[2][2], Ql[2][2];
  size_t qbase = ((size_t)(b*16 + h)*512 + q0 + wm0) * 64;
  #pragma unroll
  for (int mf=0;mf<2;++mf){
    #pragma unroll
    for (int ks=0;ks<2;++ks){
      size_t o = qbase + (size_t)(mf*16 + r)*64 + ks*32 + quad*8;
      Qh[mf][ks] = *(const bf16x8*)&qh_[o];
      Ql[mf][ks] = *(const bf16x8*)&ql_[o];
    }
  }

  const f32x4 fz = {0.f,0.f,0.f,0.f};
  f32x4 O[2][4];
  float lsum[2][4];
  #pragma unroll
  for (int mf=0;mf<2;++mf){
    #pragma unroll
    for (int e=0;e<4;++e) lsum[mf][e] = 0.f;
    #pragma unroll
    for (int nf=0;nf<4;++nf) O[mf][nf] = fz;
  }

  const float kscale = 0.125f * 1.44269504088896340736f;  // scale*log2(e)
  size_t kvb = (size_t)(b*16 + h) * NP  * 64;
  size_t nb  = (size_t)(b*16 + h) * 512 * 64;
  int sj = tid >> 4, sd0 = (tid & 15) * 4;

  // K prefetch registers (past float4 x4 / new uint4 x2)
  float4 kbuf[4];
  bool nisp = false; int nj0 = 0;
  auto issueK = [&](int itn){
    nisp = itn < npast;
    nj0 = (nisp ? itn : itn - npast) << 6;
    if (nisp){
      #pragma unroll
      for (int i=0;i<4;++i){
        int j = sj + i*16;
        kbuf[i] = *(const float4*)&pk[kvb + (size_t)(nj0 + j)*64 + sd0];
      }
    } else {
      #pragma unroll
      for (int i=0;i<2;++i){
        int j = (tid>>3) + i*32, d0 = (tid & 7)*8;
        kbuf[i] = *(const float4*)&knh[nb + (size_t)(nj0 + j)*64 + d0];
      }
    }
  };
  if (it0 < it1) issueK(it0);

  for (int it = it0; it < it1; ++it){
    bool ispc = nisp; int j0c = nj0;

    // issue V loads FIRST: consumed only after QK + softmax, max lead time
    float4  pvv[4];     // past
    ushort4 vnr[4];     // new
    if (ispc){
      #pragma unroll
      for (int i=0;i<4;++i){
        int j = sj + i*16;
        pvv[i] = *(const float4*)&pv[kvb + (size_t)(j0c + j)*64 + sd0];
      }
    } else {
      #pragma unroll
      for (int i=0;i<4;++i){
        int j = sj + i*16;
        vnr[i] = *(const ushort4*)&vnh[nb + (size_t)(j0c + j)*64 + sd0];
      }
    }

    // stage K tile from prefetched regs (issued one iteration ago)
    if (ispc){
      #pragma unroll
      for (int i=0;i<4;++i){
        int j = sj + i*16;
        float4 kv = kbuf[i];
        if (j0c + j >= Lp){ kv.x=0.f; kv.y=0.f; kv.z=0.f; kv.w=0.f; }
        ushort4 khv; khv.x=bf16rn(kv.x); khv.y=bf16rn(kv.y); khv.z=bf16rn(kv.z); khv.w=bf16rn(kv.w);
        *(ushort4*)&sK[j*72 + sd0] = khv;
      }
    } else {
      #pragma unroll
      for (int i=0;i<2;++i){
        int j = (tid>>3) + i*32, d0 = (tid & 7)*8;
        *(uint4*)&sK[j*72 + d0] = __builtin_bit_cast(uint4, kbuf[i]);
      }
    }

    // prefetch next K tile (stays in flight across the barrier below)
    if (it + 1 < it1) issueK(it + 1);

    bar_nodrain();                     // [A] sK visible; prev-iter PV done.
                                       //     NO vmcnt drain: V + next-K fly on.

    // QK^T
    f32x4 Sc[2][4];
    #pragma unroll
    for (int mf=0;mf<2;++mf){
      #pragma unroll
      for (int jf=0;jf<4;++jf) Sc[mf][jf] = fz;
    }
    __builtin_amdgcn_s_setprio(1);
    #pragma unroll
    for (int ks=0;ks<2;++ks){
      #pragma unroll
      for (int jf=0;jf<4;++jf){
        int off = (jf*16 + r)*72 + ks*32 + quad*8;
        bf16x8 kbh = *(const bf16x8*)&sK[off];
        #pragma unroll
        for (int mf=0;mf<2;++mf){
          Sc[mf][jf] = mfma16(Qh[mf][ks], kbh, Sc[mf][jf]);
          Sc[mf][jf] = mfma16(Ql[mf][ks], kbh, Sc[mf][jf]);
        }
      }
    }
    __builtin_amdgcn_s_setprio(0);

    // fixed-max softmax (pure VALU on Sc — no V dependency, hides V latency):
    // p = exp2(s*kscale - 4); accumulate l per-lane; sP writes swizzled.
    int jlim = (ispc ? TL : Ln) - j0c;
    #pragma unroll
    for (int mf=0;mf<2;++mf){
      #pragma unroll
      for (int e=0;e<4;++e){
        int row = mf*16 + quad*4 + e;
        int pbase = wid*2304 + row*72;
        float ls = 0.f;
        #pragma unroll
        for (int jf=0;jf<4;++jf){
          float sv = Sc[mf][jf][e] * kscale - 4.0f;
          sv = (jf*16 + r < jlim) ? sv : -3.0e38f;
          float pj = exp2f(sv);
          ls += pj;
          sP[pbase + swz(row, jf*16 + r)] = bf16rn(pj);
        }
        lsum[mf][e] += ls;
      }
    }

    // V^T (hi) into sVT — first V use; compiler emits counted vmcnt
    // (next-K issued after V, so K stays in flight). Swizzled writes.
    if (ispc){
      #pragma unroll
      for (int i=0;i<4;++i){
        int j = sj + i*16;
        float4 vv = pvv[i];
        if (j0c + j >= Lp){ vv.x=0.f; vv.y=0.f; vv.z=0.f; vv.w=0.f; }
        sVT[(sd0+0)*72 + swz(sd0+0, j)] = bf16rn(vv.x);
        sVT[(sd0+1)*72 + swz(sd0+1, j)] = bf16rn(vv.y);
        sVT[(sd0+2)*72 + swz(sd0+2, j)] = bf16rn(vv.z);
        sVT[(sd0+3)*72 + swz(sd0+3, j)] = bf16rn(vv.w);
      }
    } else {
      #pragma unroll
      for (int i=0;i<4;++i){
        int j = sj + i*16;
        sVT[(sd0+0)*72 + swz(sd0+0, j)] = vnr[i].x;
        sVT[(sd0+1)*72 + swz(sd0+1, j)] = vnr[i].y;
        sVT[(sd0+2)*72 + swz(sd0+2, j)] = vnr[i].z;
        sVT[(sd0+3)*72 + swz(sd0+3, j)] = vnr[i].w;
      }
    }

    bar_nodrain();                     // [B] sVT (+ own-wave sP) visible

    // O += P V
    __builtin_amdgcn_s_setprio(1);
    #pragma unroll
    for (int ks=0;ks<2;++ks){
      bf16x8 pah[2];
      #pragma unroll
      for (int mf=0;mf<2;++mf){
        int row = mf*16 + r;
        pah[mf] = *(const bf16x8*)&sP[wid*2304 + row*72 + swz(row, ks*32 + quad*8)];
      }
      #pragma unroll
      for (int nf=0;nf<4;++nf){
        int row = nf*16 + r;
        bf16x8 vbh = *(const bf16x8*)&sVT[row*72 + swz(row, ks*32 + quad*8)];
        #pragma unroll
        for (int mf=0;mf<2;++mf){
          O[mf][nf] = mfma16(pah[mf], vbh, O[mf][nf]);
        }
      }
    }
    __builtin_amdgcn_s_setprio(0);
  }

  // write partials: l (row sum over lanes) + un-normalized O (fp32)
  int pidx = ((b*16 + h)*4 + qt)*S + s;
  float* plr = pl + (size_t)pidx*128;
  float* po  = pO + (size_t)pidx*8192;
  float zadd = (s == 0) ? (float)Zar * 0.0625f : 0.f;
  #pragma unroll
  for (int mf=0;mf<2;++mf){
    #pragma unroll
    for (int e=0;e<4;++e){
      int row = wm0 + mf*16 + quad*4 + e;
      float l = lsum[mf][e];
      l += __shfl_xor(l, 1);
      l += __shfl_xor(l, 2);
      l += __shfl_xor(l, 4);
      l += __shfl_xor(l, 8);
      if (r == 0) plr[row] = l + zadd;
      #pragma unroll
      for (int nf=0;nf<4;++nf) po[row*64 + nf*16 + r] = O[mf][nf][e];
    }
  }
}

// ---------------- combine split-K partials (plain sum) ----------------
__global__ __launch_bounds__(256) void k_reduce(
    const float* __restrict__ pl, const float* __restrict__ pO,
    const int* __restrict__ plen, const int* __restrict__ cnts,
    int S, u16* __restrict__ aoh, u16* __restrict__ aol)
{
  int qt = blockIdx.x, h = blockIdx.y, b = blockIdx.z;
  int cnt = cnts[b]; int q0 = qt*128;
  if (q0 >= cnt) return;
  int Lp = min(max(plen[b], 0), NP);
  int TL = Lp + cnt;
  int Ln = max(0, TL - NP);
  int jend = min(((Lp + 63) >> 6) << 6, NP);
  int minTLP = min(TL, NP);
  int Zar = max(0, minTLP - jend);
  int npast = jend >> 6, nnew = (Ln + 63) >> 6;
  int Tt = npast + nnew;
  int qsp = (Tt + S - 1) / S;

  int tid = threadIdx.x;
  int row = tid >> 1, c0 = (tid & 1) * 32;
  int base = ((b*16 + h)*4 + qt)*S;

  float L = 0.f;
  float acc[32];
  #pragma unroll
  for (int i=0;i<32;++i) acc[i] = 0.f;
  for (int s2=0;s2<S;++s2){
    bool act = (s2*qsp < Tt) || (s2 == 0 && Zar > 0);
    if (!act) continue;
    L += pl[(size_t)(base+s2)*128 + row];
    const float4* po = (const float4*)(pO + (size_t)(base+s2)*8192 + row*64 + c0);
    #pragma unroll
    for (int i=0;i<8;++i){
      float4 v = po[i];
      acc[4*i+0] += v.x; acc[4*i+1] += v.y; acc[4*i+2] += v.z; acc[4*i+3] += v.w;
    }
  }
  float inv = 1.f / L;
  size_t o = ((size_t)b*512 + q0 + row)*1024 + h*64 + c0;
  #pragma unroll
  for (int i=0;i<8;++i){
    ushort4 hv, lv;
    u16 hh, ll;
    split2(acc[4*i+0]*inv, hh, ll); hv.x=hh; lv.x=ll;
    split2(acc[4*i+1]*inv, hh, ll); hv.y=hh; lv.y=ll;
    split2(acc[4*i+2]*inv, hh, ll); hv.z=hh; lv.z=ll;
    split2(acc[4*i+3]*inv, hh, ll); hv.w=hh; lv.w=ll;
    *(ushort4*)&aoh[o + 4*i] = hv;
    *(ushort4*)&aol[o + 4*i] = lv;
  }
}

// ---------------- output projection GEMM + bias + mask ----------------
__global__ __launch_bounds__(256) void k_oproj(
    const u16* __restrict__ ah_, const u16* __restrict__ al_,
    const u16* __restrict__ Wth, const u16* __restrict__ Wtl,
    const float* __restrict__ bo, const int* __restrict__ cnts,
    float* __restrict__ out)
{
  int n0 = blockIdx.x * 128, m0 = blockIdx.y * 128;
  int b = m0 >> 9, t0 = m0 & 511;
  int cnt = cnts[b];
  int tid = threadIdx.x;
  if (t0 >= cnt){
    float4 z4 = {0.f,0.f,0.f,0.f};
    #pragma unroll
    for (int i=0;i<16;++i){
      int v = tid + i*256;
      int row = v >> 5, c4 = (v & 31) * 4;
      *(float4*)&out[(size_t)(m0+row)*1024 + n0 + c4] = z4;
    }
    return;
  }
  const u16* Bh = Wth + 3ull*1024*1024;
  const u16* Bl = Wtl + 3ull*1024*1024;

  __shared__ u16 sA[2][128*40];
  __shared__ u16 sB[2][128*40];

  int lane = tid & 63, wid = tid >> 6;
  int r = lane & 15, quad = lane >> 4;
  int wm = (wid >> 1) * 64, wn = (wid & 1) * 64;

  const f32x4 fz = {0.f,0.f,0.f,0.f};
  f32x4 acc[4][4];
  #pragma unroll
  for (int i=0;i<4;++i){
    #pragma unroll
    for (int j=0;j<4;++j) acc[i][j] = fz;
  }

  int srow = tid >> 2, sc8 = (tid & 3) * 8;

  for (int kt = 0; kt < 32; ++kt){
    int kb = kt * 32;
    __syncthreads();
    {
      size_t ga  = (size_t)(m0 + srow) * 1024 + kb + sc8;
      size_t gb  = (size_t)(n0 + srow) * 1024 + kb + sc8;
      int lo = srow*40 + sc8, lo2 = lo + 64*40;
      *(uint4*)&sA[0][lo]  = *(const uint4*)&ah_[ga];
      *(uint4*)&sA[1][lo]  = *(const uint4*)&al_[ga];
      *(uint4*)&sB[0][lo]  = *(const uint4*)&Bh[gb];
      *(uint4*)&sB[1][lo]  = *(const uint4*)&Bl[gb];
      *(uint4*)&sA[0][lo2] = *(const uint4*)&ah_[ga + 64*1024];
      *(uint4*)&sA[1][lo2] = *(const uint4*)&al_[ga + 64*1024];
      *(uint4*)&sB[0][lo2] = *(const uint4*)&Bh[gb + 64*1024];
      *(uint4*)&sB[1][lo2] = *(const uint4*)&Bl[gb + 64*1024];
    }
    __syncthreads();
    bf16x8 ah8[4], al8[4], bh8[4], bl8[4];
    #pragma unroll
    for (int mf=0; mf<4; ++mf){
      int off = (wm + mf*16 + r)*40 + quad*8;
      ah8[mf] = *(const bf16x8*)&sA[0][off];
      al8[mf] = *(const bf16x8*)&sA[1][off];
    }
    #pragma unroll
    for (int nf=0; nf<4; ++nf){
      int off = (wn + nf*16 + r)*40 + quad*8;
      bh8[nf] = *(const bf16x8*)&sB[0][off];
      bl8[nf] = *(const bf16x8*)&sB[1][off];
    }
    #pragma unroll
    for (int mf=0; mf<4; ++mf){
      #pragma unroll
      for (int nf=0; nf<4; ++nf){
        acc[mf][nf] = mfma16(ah8[mf], bh8[nf], acc[mf][nf]);
        acc[mf][nf] = mfma16(al8[mf], bh8[nf], acc[mf][nf]);
        acc[mf][nf] = mfma16(ah8[mf], bl8[nf], acc[mf][nf]);
      }
    }
  }

  #pragma unroll
  for (int mf=0;mf<4;++mf){
    #pragma unroll
    for (int e=0;e<4;++e){
      int t = t0 + wm + mf*16 + quad*4 + e;
      float msk = (t < cnt) ? 1.f : 0.f;
      int row = m0 + wm + mf*16 + quad*4 + e;
      #pragma unroll
      for (int nf=0;nf<4;++nf){
        int gc = n0 + wn + nf*16 + r;
        out[(size_t)row*1024 + gc] = (acc[mf][nf][e] + bo[gc]) * msk;
      }
    }
  }
}

extern "C" void kernel_launch(void* const* d_in, const int* in_sizes, int n_in,
                              void* d_out, int out_size, void* d_ws, size_t ws_size,
                              hipStream_t stream) {
  (void)in_sizes; (void)n_in; (void)out_size;
  const float* x    = (const float*)d_in[0];
  const float* rcos = (const float*)d_in[1];
  const float* rsin = (const float*)d_in[2];
  const float* pk   = (const float*)d_in[3];
  const float* pv   = (const float*)d_in[4];
  const int*   plen = (const int*)d_in[5];
  const int*   cnts = (const int*)d_in[7];
  const float* Wq = (const float*)d_in[8];
  const float* bq = (const float*)d_in[9];
  const float* Wk = (const float*)d_in[10];
  const float* bk = (const float*)d_in[11];
  const float* Wv = (const float*)d_in[12];
  const float* bv = (const float*)d_in[13];
  const float* Wo = (const float*)d_in[14];
  const float* bo = (const float*)d_in[15];
  float* out = (float*)d_out;

  char* w = (char*)d_ws;
  const size_t SLOT = 8ull * 1024 * 1024;
  u16* xh  = (u16*)(w + 0*SLOT);     // later aliased as attention-out hi
  u16* xl  = (u16*)(w + 1*SLOT);     // later aliased as attention-out lo
  u16* Wth = (u16*)(w + 2*SLOT);
  u16* Wtl = (u16*)(w + 3*SLOT);
  u16* qh  = (u16*)(w + 4*SLOT);
  u16* ql  = (u16*)(w + 5*SLOT);
  u16* knh = (u16*)(w + 6*SLOT);
  u16* vnh = (u16*)(w + 7*SLOT);
  float* pl = (float*)(w + 8*SLOT);                 // 2 MB max (512*S*128 f32)
  float* pO = (float*)(w + 8*SLOT + (2ull<<20));    // 16 MB per split
  u16* aoh = xh;
  u16* aol = xl;

  // runtime split count from available workspace (fp32 partials, 16 MB/split)
  size_t used = 8*SLOT + (2ull<<20);
  int S = (int)((ws_size - used) / (16ull<<20));
  if (S > 8) S = 8;
  if (S < 1) S = 1;

  k_split_x<<<dim3(4096), dim3(256), 0, stream>>>(x, xh, xl);
  k_wsplit<<<dim3(16,16,4), dim3(256), 0, stream>>>(Wq, Wk, Wv, Wo, Wth, Wtl);
  k_qkv<<<dim3(8,32,3), dim3(256), 0, stream>>>(xh, xl, Wth, Wtl, bq, bk, bv,
                                                rcos, rsin, cnts,
                                                qh, ql, knh, vnh);
  k_attn<<<dim3(4,16,8*S), dim3(256), 0, stream>>>(qh, ql, knh, vnh,
                                                   pk, pv, plen, cnts, S, pl, pO);
  k_reduce<<<dim3(4,16,8), dim3(256), 0, stream>>>(pl, pO, plen, cnts, S, aoh, aol);
  k_oproj<<<dim3(8,32), dim3(256), 0, stream>>>(aoh, aol, Wth, Wtl, bo, cnts, out);
}

// Round 3
// 583.542 us; speedup vs baseline: 1.2539x; 1.2539x over previous
//
#include <hip/hip_runtime.h>

// RotarySelfAttention on MI355X (gfx950).
// Round 5 = round 4 resubmitted verbatim after infra failure ("container
// failed twice", no compile/correctness signal). Full fault audit done:
// bounds, aliasing order, barrier uniformity, gload_lds addressing, swizzle
// bijectivity, mask-semantics equivalence — all verified by hand.
//
// Round 4 design (post-mortem r3: +57% HBM at constant logical traffic =
// scratch spills; fix is structural):
//   - k_conv pre-converts past K/V to bf16, masked, XOR-swizzled; V stored
//     TRANSPOSED per 64x64 tile. k_qkv writes new K/V in the same format.
//   - k_attn stages tiles with global_load_lds (no staging regs, no
//     conversion, no transpose, no divergence), double-buffered,
//     2 barriers/iter; the vmcnt drain at barrier [B] lands a full
//     QK+softmax after issue (T3 minimum-2-phase pattern).
//   - swizzle both-sides-or-neither (rule 21): pre-swizzled global source +
//     linear LDS dest + swizzled ds_read.  sP swizzled by (row>>2)&7.
//   - no setprio (lockstep waves, m190).

typedef unsigned short u16;
typedef unsigned int   u32;
typedef float  f32x4  __attribute__((ext_vector_type(4)));
typedef __bf16 bf16x8 __attribute__((ext_vector_type(8)));

#define DEV static __device__ __forceinline__

constexpr int NP = 3584;

DEV u16 bf16rn(float f){
  u32 u = __float_as_uint(f);
  return (u16)((u + 0x7fffu + ((u >> 16) & 1u)) >> 16);
}
DEV float bf2f(u16 h){ return __uint_as_float((u32)h << 16); }
DEV void split2(float f, u16 &h, u16 &l){ h = bf16rn(f); l = bf16rn(f - bf2f(h)); }

DEV f32x4 mfma16(bf16x8 a, bf16x8 b, f32x4 c){
  return __builtin_amdgcn_mfma_f32_16x16x32_bf16(a, b, c, 0, 0, 0);
}

DEV ushort4 cvt4(float4 v){
  ushort4 h; h.x=bf16rn(v.x); h.y=bf16rn(v.y); h.z=bf16rn(v.z); h.w=bf16rn(v.w); return h;
}

// async global->LDS, 16B per lane; LDS base must be wave-uniform.
DEV void gload_lds16(const u16* g, u16* l){
  __builtin_amdgcn_global_load_lds((const __attribute__((address_space(1))) void*)g,
                                   (__attribute__((address_space(3))) void*)l, 16, 0, 0);
}

// ---------------- split x into hi/lo bf16 ----------------
__global__ __launch_bounds__(256) void k_split_x(const float* __restrict__ x,
                                                 u16* __restrict__ xh, u16* __restrict__ xl){
  int i = blockIdx.x * 256 + threadIdx.x;
  float4 v = ((const float4*)x)[i];
  u16 h0,l0,h1,l1,h2,l2,h3,l3;
  split2(v.x,h0,l0); split2(v.y,h1,l1); split2(v.z,h2,l2); split2(v.w,h3,l3);
  ushort4 hv; hv.x=h0; hv.y=h1; hv.z=h2; hv.w=h3;
  ushort4 lv; lv.x=l0; lv.y=l1; lv.z=l2; lv.w=l3;
  ((ushort4*)xh)[i] = hv; ((ushort4*)xl)[i] = lv;
}

// ------------- transpose + split weights: Wt[n][k] = W[k][n] -------------
__global__ __launch_bounds__(256) void k_wsplit(const float* __restrict__ w0, const float* __restrict__ w1,
                                                const float* __restrict__ w2, const float* __restrict__ w3,
                                                u16* __restrict__ Wth, u16* __restrict__ Wtl){
  __shared__ float tl[64][65];
  int z = blockIdx.z;
  const float* W = (z==0) ? w0 : (z==1) ? w1 : (z==2) ? w2 : w3;
  u16* oh = Wth + (size_t)z * (1024*1024);
  u16* ol = Wtl + (size_t)z * (1024*1024);
  int n0 = blockIdx.x*64, k0 = blockIdx.y*64;
  int tid = threadIdx.x;
  #pragma unroll
  for (int i=0;i<16;++i){
    int idx = i*256 + tid; int rr = idx >> 6, cc = idx & 63;
    tl[rr][cc] = W[(size_t)(k0+rr)*1024 + n0 + cc];
  }
  __syncthreads();
  #pragma unroll
  for (int i=0;i<16;++i){
    int idx = i*256 + tid; int rr = idx >> 6, cc = idx & 63;
    u16 h,l; split2(tl[cc][rr], h, l);
    size_t o = (size_t)(n0+rr)*1024 + k0 + cc;
    oh[o] = h; ol[o] = l;
  }
}

// ---------------- QKV projection GEMM + bias + RoPE + mask ----------------
// zi==0 -> qh/ql (row-major hi/lo)
// zi==1 -> knt   (tiled [bh][tn][64 j][64 d], d swizzled by j&7)
// zi==2 -> vnt   (tiled [bh][tn][64 d][64 j], j swizzled by d&7)  == V^T
__global__ __launch_bounds__(256) void k_qkv(
    const u16* __restrict__ xh, const u16* __restrict__ xl,
    const u16* __restrict__ Wth, const u16* __restrict__ Wtl,
    const float* __restrict__ bq, const float* __restrict__ bk, const float* __restrict__ bv,
    const float* __restrict__ rcos, const float* __restrict__ rsin,
    const int* __restrict__ cnts,
    u16* __restrict__ qh, u16* __restrict__ ql,
    u16* __restrict__ knt, u16* __restrict__ vnt)
{
  int zi = blockIdx.z;
  int n0 = blockIdx.x * 128, m0 = blockIdx.y * 128;
  int b = m0 >> 9, t0 = m0 & 511;
  int cnt = cnts[b];
  if (t0 >= cnt) return;
  const u16* Bh = Wth + (size_t)zi * (1024*1024);
  const u16* Bl = Wtl + (size_t)zi * (1024*1024);
  const float* bias = (zi==0) ? bq : (zi==1) ? bk : bv;

  __shared__ u16 sA[2][128*40];
  __shared__ u16 sB[2][128*40];

  int tid = threadIdx.x, lane = tid & 63, wid = tid >> 6;
  int r = lane & 15, quad = lane >> 4;
  int wm = (wid >> 1) * 64, wn = (wid & 1) * 64;

  const f32x4 fz = {0.f,0.f,0.f,0.f};
  f32x4 acc[4][4];
  #pragma unroll
  for (int i=0;i<4;++i){
    #pragma unroll
    for (int j=0;j<4;++j) acc[i][j] = fz;
  }

  int srow = tid >> 2, sc8 = (tid & 3) * 8;

  for (int kt = 0; kt < 32; ++kt){
    int kb = kt * 32;
    __syncthreads();
    {
      size_t ga  = (size_t)(m0 + srow) * 1024 + kb + sc8;
      size_t gb  = (size_t)(n0 + srow) * 1024 + kb + sc8;
      int lo = srow*40 + sc8, lo2 = lo + 64*40;
      *(uint4*)&sA[0][lo]  = *(const uint4*)&xh[ga];
      *(uint4*)&sA[1][lo]  = *(const uint4*)&xl[ga];
      *(uint4*)&sB[0][lo]  = *(const uint4*)&Bh[gb];
      *(uint4*)&sB[1][lo]  = *(const uint4*)&Bl[gb];
      *(uint4*)&sA[0][lo2] = *(const uint4*)&xh[ga + 64*1024];
      *(uint4*)&sA[1][lo2] = *(const uint4*)&xl[ga + 64*1024];
      *(uint4*)&sB[0][lo2] = *(const uint4*)&Bh[gb + 64*1024];
      *(uint4*)&sB[1][lo2] = *(const uint4*)&Bl[gb + 64*1024];
    }
    __syncthreads();
    bf16x8 ah[4], al[4], bh8[4], bl8[4];
    #pragma unroll
    for (int mf=0; mf<4; ++mf){
      int off = (wm + mf*16 + r)*40 + quad*8;
      ah[mf] = *(const bf16x8*)&sA[0][off];
      al[mf] = *(const bf16x8*)&sA[1][off];
    }
    #pragma unroll
    for (int nf=0; nf<4; ++nf){
      int off = (wn + nf*16 + r)*40 + quad*8;
      bh8[nf] = *(const bf16x8*)&sB[0][off];
      bl8[nf] = *(const bf16x8*)&sB[1][off];
    }
    #pragma unroll
    for (int mf=0; mf<4; ++mf){
      #pragma unroll
      for (int nf=0; nf<4; ++nf){
        acc[mf][nf] = mfma16(ah[mf], bh8[nf], acc[mf][nf]);
        acc[mf][nf] = mfma16(al[mf], bh8[nf], acc[mf][nf]);
        acc[mf][nf] = mfma16(ah[mf], bl8[nf], acc[mf][nf]);
      }
    }
  }

  float vals[4][4][4];
  #pragma unroll
  for (int mf=0;mf<4;++mf){
    #pragma unroll
    for (int nf=0;nf<4;++nf){
      float bb = bias[n0 + wn + nf*16 + r];
      #pragma unroll
      for (int e=0;e<4;++e) vals[mf][nf][e] = acc[mf][nf][e] + bb;
    }
  }
  if (zi < 2){
    #pragma unroll
    for (int mf=0;mf<4;++mf){
      #pragma unroll
      for (int e=0;e<4;++e){
        int t = t0 + wm + mf*16 + quad*4 + e;
        #pragma unroll
        for (int nf=0;nf<2;++nf){
          int d = nf*16 + r;
          float c1 = rcos[t*64 + d],      s1 = rsin[t*64 + d];
          float c2 = rcos[t*64 + d + 32], s2 = rsin[t*64 + d + 32];
          float x1 = vals[mf][nf][e], x2 = vals[mf][nf+2][e];
          vals[mf][nf][e]   = x1*c1 - x2*s1;
          vals[mf][nf+2][e] = x2*c2 + x1*s2;
        }
      }
    }
  }
  #pragma unroll
  for (int mf=0;mf<4;++mf){
    #pragma unroll
    for (int e=0;e<4;++e){
      int t = t0 + wm + mf*16 + quad*4 + e;
      float msk = (t < cnt) ? 1.f : 0.f;
      #pragma unroll
      for (int nf=0;nf<4;++nf){
        int gc = n0 + wn + nf*16 + r;
        int head = gc >> 6, d = gc & 63;
        float v = vals[mf][nf][e] * msk;
        u16 hh, ll; split2(v, hh, ll);
        size_t bh8t = (size_t)(b*16 + head)*8;
        if (zi == 0){
          size_t o = ((size_t)(b*16 + head)*512 + t)*64 + d;
          qh[o] = hh; ql[o] = ll;
        } else if (zi == 1){
          size_t o = ((bh8t + (t>>6))*64 + (t&63))*64 + (d ^ ((t&7)<<3));
          knt[o] = hh;
        } else {
          size_t o = ((bh8t + (t>>6))*64 + d)*64 + ((t&63) ^ ((d&7)<<3));
          vnt[o] = hh;
        }
      }
    }
  }
}

// ------- past K/V -> bf16, masked, swizzled; V transposed per tile -------
// ckh: [bh][3584 j][64 d], d swizzled by j&7 (row-major == tiled)
// cvt: [bh][56 t][64 d][64 j], j swizzled by d&7  (V^T)
__global__ __launch_bounds__(256) void k_conv(
    const float* __restrict__ pk, const float* __restrict__ pv,
    const int* __restrict__ plen,
    u16* __restrict__ ckh, u16* __restrict__ cvt)
{
  int t = blockIdx.x, h = blockIdx.y, b = blockIdx.z;
  int Lp = min(max(plen[b], 0), NP);
  int jend = min(((Lp + 63) >> 6) << 6, NP);
  if (t*64 >= jend) return;
  int tid = threadIdx.x;
  int bh = b*16 + h;
  int row = tid >> 2, cg = (tid & 3) * 16;
  int jj = t*64 + row;
  size_t src = ((size_t)bh*NP + jj)*64;

  __shared__ float tl[64][65];

  float4 kv4[4], vv4[4];
  #pragma unroll
  for (int i=0;i<4;++i){
    kv4[i] = *(const float4*)&pk[src + cg + i*4];
    vv4[i] = *(const float4*)&pv[src + cg + i*4];
  }
  if (jj >= Lp){
    float4 z4 = {0.f,0.f,0.f,0.f};
    #pragma unroll
    for (int i=0;i<4;++i){ kv4[i]=z4; vv4[i]=z4; }
  }
  // K store (swizzled)
  size_t kdst = ((size_t)bh*NP + jj)*64;
  #pragma unroll
  for (int i=0;i<4;++i){
    int c4 = cg + i*4;
    *(ushort4*)&ckh[kdst + (c4 ^ ((jj&7)<<3))] = cvt4(kv4[i]);
  }
  // V to LDS (row-major f32), then read transposed
  #pragma unroll
  for (int i=0;i<4;++i){
    tl[row][cg+i*4+0] = vv4[i].x;
    tl[row][cg+i*4+1] = vv4[i].y;
    tl[row][cg+i*4+2] = vv4[i].z;
    tl[row][cg+i*4+3] = vv4[i].w;
  }
  __syncthreads();
  int d = tid >> 2, jg = (tid & 3) * 16;
  size_t vdst = (((size_t)bh*56 + t)*64 + d)*64;
  #pragma unroll
  for (int i=0;i<4;++i){
    int j4 = jg + i*4;
    ushort4 hv;
    hv.x = bf16rn(tl[j4+0][d]);
    hv.y = bf16rn(tl[j4+1][d]);
    hv.z = bf16rn(tl[j4+2][d]);
    hv.w = bf16rn(tl[j4+3][d]);
    *(ushort4*)&cvt[vdst + (j4 ^ ((d&7)<<3))] = hv;
  }
}

// ---------------- flash attention, split-K, fixed-max softmax ----------------
__global__ __launch_bounds__(256,3) void k_attn(
    const u16* __restrict__ qh_, const u16* __restrict__ ql_,
    const u16* __restrict__ knt, const u16* __restrict__ vnt,
    const u16* __restrict__ ckh, const u16* __restrict__ cvt,
    const int* __restrict__ plen, const int* __restrict__ cnts,
    int S, float* __restrict__ pl, float* __restrict__ pO)
{
  int qt = blockIdx.x, h = blockIdx.y;
  int zb = blockIdx.z;
  int b = zb / S, s = zb - b * S;
  int cnt = cnts[b];
  int q0 = qt * 128;
  if (q0 >= cnt) return;
  int Lp = min(max(plen[b], 0), NP);
  int TL = Lp + cnt;
  int Ln = max(0, TL - NP);
  int jend = min(((Lp + 63) >> 6) << 6, NP);
  int minTLP = min(TL, NP);
  int Zar = max(0, minTLP - jend);
  int npast = jend >> 6, nnew = (Ln + 63) >> 6;
  int Tt = npast + nnew;
  int TLu = min(TL, jend) + Ln;          // unified valid-key prefix length
  int qsp = (Tt + S - 1) / S;
  int it0 = s * qsp, it1 = min(Tt, it0 + qsp);
  bool hasZ = (s == 0 && Zar > 0);
  if (it0 >= it1 && !hasZ) return;

  __shared__ __align__(16) u16 sK [2][4096];
  __shared__ __align__(16) u16 sVT[2][4096];
  __shared__ __align__(16) u16 sP [4][2048];

  int tid = threadIdx.x, lane = tid & 63, wid = tid >> 6;
  int r = lane & 15, quad = lane >> 4;
  int wm0 = wid * 32;
  int bh = b*16 + h;

  bf16x8 Qh[2][2], Ql[2][2];
  size_t qbase = ((size_t)bh*512 + q0 + wm0) * 64;
  #pragma unroll
  for (int mf=0;mf<2;++mf){
    #pragma unroll
    for (int ks=0;ks<2;++ks){
      size_t o = qbase + (size_t)(mf*16 + r)*64 + ks*32 + quad*8;
      Qh[mf][ks] = *(const bf16x8*)&qh_[o];
      Ql[mf][ks] = *(const bf16x8*)&ql_[o];
    }
  }

  const f32x4 fz = {0.f,0.f,0.f,0.f};
  f32x4 O[2][4];
  float lsum[2][4];
  #pragma unroll
  for (int mf=0;mf<2;++mf){
    #pragma unroll
    for (int e=0;e<4;++e) lsum[mf][e] = 0.f;
    #pragma unroll
    for (int nf=0;nf<4;++nf) O[mf][nf] = fz;
  }

  const float kscale = 0.125f * 1.44269504088896340736f;  // scale*log2(e)
  int ub = wid * 512;   // per-wave staging base (u16 elems)

  auto stage = [&](int pp, int it){
    const u16* ks; const u16* vs;
    if (it < npast){
      ks = ckh + ((size_t)bh*NP + (size_t)it*64)*64;
      vs = cvt + ((size_t)bh*56 + it)*4096;
    } else {
      ks = knt + ((size_t)bh*8 + (it - npast))*4096;
      vs = vnt + ((size_t)bh*8 + (it - npast))*4096;
    }
    gload_lds16(ks + ub + lane*8,        &sK [pp][ub]);
    gload_lds16(ks + ub + 2048 + lane*8, &sK [pp][ub + 2048]);
    gload_lds16(vs + ub + lane*8,        &sVT[pp][ub]);
    gload_lds16(vs + ub + 2048 + lane*8, &sVT[pp][ub + 2048]);
  };

  int p = 0;
  if (it0 < it1) stage(0, it0);
  __syncthreads();

  for (int it = it0; it < it1; ++it){
    if (it + 1 < it1) stage(p^1, it + 1);   // async, drains at barrier [B]

    // QK^T from sK[p] (swizzled reads, conflict-free)
    f32x4 Sc[2][4];
    #pragma unroll
    for (int mf=0;mf<2;++mf){
      #pragma unroll
      for (int jf=0;jf<4;++jf) Sc[mf][jf] = fz;
    }
    #pragma unroll
    for (int ks=0;ks<2;++ks){
      #pragma unroll
      for (int jf=0;jf<4;++jf){
        int jr = jf*16 + r;
        int off = jr*64 + ((ks*32 + quad*8) ^ ((jr&7)<<3));
        bf16x8 kbh = *(const bf16x8*)&sK[p][off];
        #pragma unroll
        for (int mf=0;mf<2;++mf){
          Sc[mf][jf] = mfma16(Qh[mf][ks], kbh, Sc[mf][jf]);
          Sc[mf][jf] = mfma16(Ql[mf][ks], kbh, Sc[mf][jf]);
        }
      }
    }

    // fixed-max softmax: p = exp2(s*kscale - 4); sP swizzled by (row>>2)&7
    int jlim = TLu - it*64;
    #pragma unroll
    for (int mf=0;mf<2;++mf){
      #pragma unroll
      for (int e=0;e<4;++e){
        int row = mf*16 + quad*4 + e;
        int sw = ((row>>2)&7) << 3;
        float ls = 0.f;
        #pragma unroll
        for (int jf=0;jf<4;++jf){
          float sv = Sc[mf][jf][e] * kscale - 4.0f;
          sv = (jf*16 + r < jlim) ? sv : -3.0e38f;
          float pj = exp2f(sv);
          ls += pj;
          __bf16 pb = (__bf16)pj;
          sP[wid][row*64 + ((jf*16 + r) ^ sw)] = __builtin_bit_cast(u16, pb);
        }
        lsum[mf][e] += ls;
      }
    }
    __syncthreads();   // [B] stage(p^1) landed (drain hidden behind QK+softmax);
                       //     sP visible; all QK reads of sK[p] done

    // O += P V from sVT[p]
    #pragma unroll
    for (int ks=0;ks<2;++ks){
      bf16x8 pah[2];
      #pragma unroll
      for (int mf=0;mf<2;++mf){
        int row = mf*16 + r;
        pah[mf] = *(const bf16x8*)&sP[wid][row*64 + ((ks*32 + quad*8) ^ (((row>>2)&7)<<3))];
      }
      #pragma unroll
      for (int nf=0;nf<4;++nf){
        int d = nf*16 + r;
        bf16x8 vbh = *(const bf16x8*)&sVT[p][d*64 + ((ks*32 + quad*8) ^ ((d&7)<<3))];
        #pragma unroll
        for (int mf=0;mf<2;++mf){
          O[mf][nf] = mfma16(pah[mf], vbh, O[mf][nf]);
        }
      }
    }
    __syncthreads();   // [C] PV reads done before next iter's stage overwrites
    p ^= 1;
  }

  // write partials: l (row sum over lanes) + un-normalized O (fp32)
  int pidx = ((b*16 + h)*4 + qt)*S + s;
  float* plr = pl + (size_t)pidx*128;
  float* po  = pO + (size_t)pidx*8192;
  float zadd = (s == 0) ? (float)Zar * 0.0625f : 0.f;
  #pragma unroll
  for (int mf=0;mf<2;++mf){
    #pragma unroll
    for (int e=0;e<4;++e){
      int row = wm0 + mf*16 + quad*4 + e;
      float l = lsum[mf][e];
      l += __shfl_xor(l, 1);
      l += __shfl_xor(l, 2);
      l += __shfl_xor(l, 4);
      l += __shfl_xor(l, 8);
      if (r == 0) plr[row] = l + zadd;
      #pragma unroll
      for (int nf=0;nf<4;++nf) po[row*64 + nf*16 + r] = O[mf][nf][e];
    }
  }
}

// ---------------- combine split-K partials (plain sum) ----------------
__global__ __launch_bounds__(256) void k_reduce(
    const float* __restrict__ pl, const float* __restrict__ pO,
    const int* __restrict__ plen, const int* __restrict__ cnts,
    int S, u16* __restrict__ aoh, u16* __restrict__ aol)
{
  int qt = blockIdx.x, h = blockIdx.y, b = blockIdx.z;
  int cnt = cnts[b]; int q0 = qt*128;
  if (q0 >= cnt) return;
  int Lp = min(max(plen[b], 0), NP);
  int TL = Lp + cnt;
  int Ln = max(0, TL - NP);
  int jend = min(((Lp + 63) >> 6) << 6, NP);
  int minTLP = min(TL, NP);
  int Zar = max(0, minTLP - jend);
  int npast = jend >> 6, nnew = (Ln + 63) >> 6;
  int Tt = npast + nnew;
  int qsp = (Tt + S - 1) / S;

  int tid = threadIdx.x;
  int row = tid >> 1, c0 = (tid & 1) * 32;
  int base = ((b*16 + h)*4 + qt)*S;

  float L = 0.f;
  float acc[32];
  #pragma unroll
  for (int i=0;i<32;++i) acc[i] = 0.f;
  for (int s2=0;s2<S;++s2){
    bool act = (s2*qsp < Tt) || (s2 == 0 && Zar > 0);
    if (!act) continue;
    L += pl[(size_t)(base+s2)*128 + row];
    const float4* po = (const float4*)(pO + (size_t)(base+s2)*8192 + row*64 + c0);
    #pragma unroll
    for (int i=0;i<8;++i){
      float4 v = po[i];
      acc[4*i+0] += v.x; acc[4*i+1] += v.y; acc[4*i+2] += v.z; acc[4*i+3] += v.w;
    }
  }
  float inv = 1.f / L;
  size_t o = ((size_t)b*512 + q0 + row)*1024 + h*64 + c0;
  #pragma unroll
  for (int i=0;i<8;++i){
    ushort4 hv, lv;
    u16 hh, ll;
    split2(acc[4*i+0]*inv, hh, ll); hv.x=hh; lv.x=ll;
    split2(acc[4*i+1]*inv, hh, ll); hv.y=hh; lv.y=ll;
    split2(acc[4*i+2]*inv, hh, ll); hv.z=hh; lv.z=ll;
    split2(acc[4*i+3]*inv, hh, ll); hv.w=hh; lv.w=ll;
    *(ushort4*)&aoh[o + 4*i] = hv;
    *(ushort4*)&aol[o + 4*i] = lv;
  }
}

// ---------------- output projection GEMM + bias + mask ----------------
__global__ __launch_bounds__(256) void k_oproj(
    const u16* __restrict__ ah_, const u16* __restrict__ al_,
    const u16* __restrict__ Wth, const u16* __restrict__ Wtl,
    const float* __restrict__ bo, const int* __restrict__ cnts,
    float* __restrict__ out)
{
  int n0 = blockIdx.x * 128, m0 = blockIdx.y * 128;
  int b = m0 >> 9, t0 = m0 & 511;
  int cnt = cnts[b];
  int tid = threadIdx.x;
  if (t0 >= cnt){
    float4 z4 = {0.f,0.f,0.f,0.f};
    #pragma unroll
    for (int i=0;i<16;++i){
      int v = tid + i*256;
      int row = v >> 5, c4 = (v & 31) * 4;
      *(float4*)&out[(size_t)(m0+row)*1024 + n0 + c4] = z4;
    }
    return;
  }
  const u16* Bh = Wth + 3ull*1024*1024;
  const u16* Bl = Wtl + 3ull*1024*1024;

  __shared__ u16 sA[2][128*40];
  __shared__ u16 sB[2][128*40];

  int lane = tid & 63, wid = tid >> 6;
  int r = lane & 15, quad = lane >> 4;
  int wm = (wid >> 1) * 64, wn = (wid & 1) * 64;

  const f32x4 fz = {0.f,0.f,0.f,0.f};
  f32x4 acc[4][4];
  #pragma unroll
  for (int i=0;i<4;++i){
    #pragma unroll
    for (int j=0;j<4;++j) acc[i][j] = fz;
  }

  int srow = tid >> 2, sc8 = (tid & 3) * 8;

  for (int kt = 0; kt < 32; ++kt){
    int kb = kt * 32;
    __syncthreads();
    {
      size_t ga  = (size_t)(m0 + srow) * 1024 + kb + sc8;
      size_t gb  = (size_t)(n0 + srow) * 1024 + kb + sc8;
      int lo = srow*40 + sc8, lo2 = lo + 64*40;
      *(uint4*)&sA[0][lo]  = *(const uint4*)&ah_[ga];
      *(uint4*)&sA[1][lo]  = *(const uint4*)&al_[ga];
      *(uint4*)&sB[0][lo]  = *(const uint4*)&Bh[gb];
      *(uint4*)&sB[1][lo]  = *(const uint4*)&Bl[gb];
      *(uint4*)&sA[0][lo2] = *(const uint4*)&ah_[ga + 64*1024];
      *(uint4*)&sA[1][lo2] = *(const uint4*)&al_[ga + 64*1024];
      *(uint4*)&sB[0][lo2] = *(const uint4*)&Bh[gb + 64*1024];
      *(uint4*)&sB[1][lo2] = *(const uint4*)&Bl[gb + 64*1024];
    }
    __syncthreads();
    bf16x8 ah8[4], al8[4], bh8[4], bl8[4];
    #pragma unroll
    for (int mf=0; mf<4; ++mf){
      int off = (wm + mf*16 + r)*40 + quad*8;
      ah8[mf] = *(const bf16x8*)&sA[0][off];
      al8[mf] = *(const bf16x8*)&sA[1][off];
    }
    #pragma unroll
    for (int nf=0; nf<4; ++nf){
      int off = (wn + nf*16 + r)*40 + quad*8;
      bh8[nf] = *(const bf16x8*)&sB[0][off];
      bl8[nf] = *(const bf16x8*)&sB[1][off];
    }
    #pragma unroll
    for (int mf=0; mf<4; ++mf){
      #pragma unroll
      for (int nf=0; nf<4; ++nf){
        acc[mf][nf] = mfma16(ah8[mf], bh8[nf], acc[mf][nf]);
        acc[mf][nf] = mfma16(al8[mf], bh8[nf], acc[mf][nf]);
        acc[mf][nf] = mfma16(ah8[mf], bl8[nf], acc[mf][nf]);
      }
    }
  }

  #pragma unroll
  for (int mf=0;mf<4;++mf){
    #pragma unroll
    for (int e=0;e<4;++e){
      int t = t0 + wm + mf*16 + quad*4 + e;
      float msk = (t < cnt) ? 1.f : 0.f;
      int row = m0 + wm + mf*16 + quad*4 + e;
      #pragma unroll
      for (int nf=0;nf<4;++nf){
        int gc = n0 + wn + nf*16 + r;
        out[(size_t)row*1024 + gc] = (acc[mf][nf][e] + bo[gc]) * msk;
      }
    }
  }
}

extern "C" void kernel_launch(void* const* d_in, const int* in_sizes, int n_in,
                              void* d_out, int out_size, void* d_ws, size_t ws_size,
                              hipStream_t stream) {
  (void)in_sizes; (void)n_in; (void)out_size;
  const float* x    = (const float*)d_in[0];
  const float* rcos = (const float*)d_in[1];
  const float* rsin = (const float*)d_in[2];
  const float* pk   = (const float*)d_in[3];
  const float* pv   = (const float*)d_in[4];
  const int*   plen = (const int*)d_in[5];
  const int*   cnts = (const int*)d_in[7];
  const float* Wq = (const float*)d_in[8];
  const float* bq = (const float*)d_in[9];
  const float* Wk = (const float*)d_in[10];
  const float* bk = (const float*)d_in[11];
  const float* Wv = (const float*)d_in[12];
  const float* bv = (const float*)d_in[13];
  const float* Wo = (const float*)d_in[14];
  const float* bo = (const float*)d_in[15];
  float* out = (float*)d_out;

  char* w = (char*)d_ws;
  const size_t MB = 1ull << 20;
  u16* Wth = (u16*)(w + 0*MB);        // 8 MB (4 matrices, hi)
  u16* Wtl = (u16*)(w + 8*MB);        // 8 MB (lo)
  u16* qh  = (u16*)(w + 16*MB);       // 8 MB
  u16* ql  = (u16*)(w + 24*MB);       // 8 MB
  u16* knt = (u16*)(w + 32*MB);       // 8 MB  new-K tiled/swizzled
  u16* vnt = (u16*)(w + 40*MB);       // 8 MB  new-V^T tiled/swizzled
  u16* ckh = (u16*)(w + 48*MB);       // 56 MB past-K bf16 swizzled
  u16* xh  = (u16*)(w + 48*MB);       //  (alias: x hi, dead before k_conv)
  u16* xl  = (u16*)(w + 56*MB);       //  (alias: x lo)
  u16* cvt = (u16*)(w + 104*MB);      // 56 MB past-V^T bf16 tiled/swizzled
  float* pl = (float*)(w + 160*MB);   // 2 MB
  float* pO = (float*)(w + 162*MB);   // 16 MB per split
  u16* aoh = xh;                      // attn-out hi (ckh dead after k_attn)
  u16* aol = xl;

  int S = (int)((ws_size - 162*MB) / (16*MB));
  if (S > 8) S = 8;
  if (S < 1) S = 1;

  k_split_x<<<dim3(4096), dim3(256), 0, stream>>>(x, xh, xl);
  k_wsplit<<<dim3(16,16,4), dim3(256), 0, stream>>>(Wq, Wk, Wv, Wo, Wth, Wtl);
  k_qkv<<<dim3(8,32,3), dim3(256), 0, stream>>>(xh, xl, Wth, Wtl, bq, bk, bv,
                                                rcos, rsin, cnts,
                                                qh, ql, knt, vnt);
  k_conv<<<dim3(56,16,8), dim3(256), 0, stream>>>(pk, pv, plen, ckh, cvt);
  k_attn<<<dim3(4,16,8*S), dim3(256), 0, stream>>>(qh, ql, knt, vnt, ckh, cvt,
                                                   plen, cnts, S, pl, pO);
  k_reduce<<<dim3(4,16,8), dim3(256), 0, stream>>>(pl, pO, plen, cnts, S, aoh, aol);
  k_oproj<<<dim3(8,32), dim3(256), 0, stream>>>(aoh, aol, Wth, Wtl, bo, cnts, out);
}

// Round 4
// 554.221 us; speedup vs baseline: 1.3203x; 1.0529x over previous
//
#include <hip/hip_runtime.h>

// RotarySelfAttention on MI355X (gfx950).
// Round 6: k_qkv / k_oproj K-loop rewrite (k_attn/k_conv/k_reduce frozen).
//   Post-mortem r5: k_attn fixed (<139us); k_qkv now largest (140us) with
//   MfmaUtil 12 / VALU 10 / HBM 13 / Occ 6.4 => latency-bound. Cause: the
//   2-barrier register-staged K-loop drains vmcnt(0) right after issuing
//   the staging loads, exposing full memory latency x32 iters at ~1.9
//   active blocks/CU.
//   - global_load_lds(16B) + double-buffered LDS, ONE barrier per K-step:
//     stage(next) issued before compute => drain lands a full ds_read+MFMA
//     phase after issue (T3 minimum-2-phase). Zero staging VGPRs.
//   - BK=32 u16 tiles: wave reads tile a contiguous 1KB span => bank-
//     conflict-free with linear layout (no swizzle, source stays coalesced).
//   - 2D XCD-locality remap of (n-tile, m-tile) to cut A-panel refetch.
//   - __launch_bounds__(256,2): LDS 64KB binds at 2 blocks/CU; no spills.

typedef unsigned short u16;
typedef unsigned int   u32;
typedef float  f32x4  __attribute__((ext_vector_type(4)));
typedef __bf16 bf16x8 __attribute__((ext_vector_type(8)));

#define DEV static __device__ __forceinline__

constexpr int NP = 3584;

DEV u16 bf16rn(float f){
  u32 u = __float_as_uint(f);
  return (u16)((u + 0x7fffu + ((u >> 16) & 1u)) >> 16);
}
DEV float bf2f(u16 h){ return __uint_as_float((u32)h << 16); }
DEV void split2(float f, u16 &h, u16 &l){ h = bf16rn(f); l = bf16rn(f - bf2f(h)); }

DEV f32x4 mfma16(bf16x8 a, bf16x8 b, f32x4 c){
  return __builtin_amdgcn_mfma_f32_16x16x32_bf16(a, b, c, 0, 0, 0);
}

DEV ushort4 cvt4(float4 v){
  ushort4 h; h.x=bf16rn(v.x); h.y=bf16rn(v.y); h.z=bf16rn(v.z); h.w=bf16rn(v.w); return h;
}

// async global->LDS, 16B per lane; LDS base must be wave-uniform.
DEV void gload_lds16(const u16* g, u16* l){
  __builtin_amdgcn_global_load_lds((const __attribute__((address_space(1))) void*)g,
                                   (__attribute__((address_space(3))) void*)l, 16, 0, 0);
}

// ---------------- split x into hi/lo bf16 ----------------
__global__ __launch_bounds__(256) void k_split_x(const float* __restrict__ x,
                                                 u16* __restrict__ xh, u16* __restrict__ xl){
  int i = blockIdx.x * 256 + threadIdx.x;
  float4 v = ((const float4*)x)[i];
  u16 h0,l0,h1,l1,h2,l2,h3,l3;
  split2(v.x,h0,l0); split2(v.y,h1,l1); split2(v.z,h2,l2); split2(v.w,h3,l3);
  ushort4 hv; hv.x=h0; hv.y=h1; hv.z=h2; hv.w=h3;
  ushort4 lv; lv.x=l0; lv.y=l1; lv.z=l2; lv.w=l3;
  ((ushort4*)xh)[i] = hv; ((ushort4*)xl)[i] = lv;
}

// ------------- transpose + split weights: Wt[n][k] = W[k][n] -------------
__global__ __launch_bounds__(256) void k_wsplit(const float* __restrict__ w0, const float* __restrict__ w1,
                                                const float* __restrict__ w2, const float* __restrict__ w3,
                                                u16* __restrict__ Wth, u16* __restrict__ Wtl){
  __shared__ float tl[64][65];
  int z = blockIdx.z;
  const float* W = (z==0) ? w0 : (z==1) ? w1 : (z==2) ? w2 : w3;
  u16* oh = Wth + (size_t)z * (1024*1024);
  u16* ol = Wtl + (size_t)z * (1024*1024);
  int n0 = blockIdx.x*64, k0 = blockIdx.y*64;
  int tid = threadIdx.x;
  #pragma unroll
  for (int i=0;i<16;++i){
    int idx = i*256 + tid; int rr = idx >> 6, cc = idx & 63;
    tl[rr][cc] = W[(size_t)(k0+rr)*1024 + n0 + cc];
  }
  __syncthreads();
  #pragma unroll
  for (int i=0;i<16;++i){
    int idx = i*256 + tid; int rr = idx >> 6, cc = idx & 63;
    u16 h,l; split2(tl[cc][rr], h, l);
    size_t o = (size_t)(n0+rr)*1024 + k0 + cc;
    oh[o] = h; ol[o] = l;
  }
}

// ---------------- QKV projection GEMM + bias + RoPE + mask ----------------
// zi==0 -> qh/ql (row-major hi/lo)
// zi==1 -> knt   (tiled [bh][tn][64 j][64 d], d swizzled by j&7)
// zi==2 -> vnt   (tiled [bh][tn][64 d][64 j], j swizzled by d&7)  == V^T
__global__ __launch_bounds__(256,2) void k_qkv(
    const u16* __restrict__ xh, const u16* __restrict__ xl,
    const u16* __restrict__ Wth, const u16* __restrict__ Wtl,
    const float* __restrict__ bq, const float* __restrict__ bk, const float* __restrict__ bv,
    const float* __restrict__ rcos, const float* __restrict__ rsin,
    const int* __restrict__ cnts,
    u16* __restrict__ qh, u16* __restrict__ ql,
    u16* __restrict__ knt, u16* __restrict__ vnt)
{
  int zi = blockIdx.z;
  // 2D XCD-locality remap: XCD (= bx%8 group) gets 2 n-panels x 16 m-tiles
  int bx = blockIdx.x, by = blockIdx.y;
  int n0 = ((bx & 3)*2 + (by & 1)) * 128;
  int m0 = ((bx >> 2)*16 + (by >> 1)) * 128;
  int b = m0 >> 9, t0 = m0 & 511;
  int cnt = cnts[b];
  if (t0 >= cnt) return;
  const u16* Bh = Wth + (size_t)zi * (1024*1024);
  const u16* Bl = Wtl + (size_t)zi * (1024*1024);
  const float* bias = (zi==0) ? bq : (zi==1) ? bk : bv;

  // [dbuf][hi/lo][128 rows x 32 cols] u16, linear (BK=32 is conflict-free)
  __shared__ __align__(16) u16 sA[2][2][4096];
  __shared__ __align__(16) u16 sB[2][2][4096];

  int tid = threadIdx.x, lane = tid & 63, wid = tid >> 6;
  int r = lane & 15, quad = lane >> 4;
  int wm = (wid >> 1) * 64, wn = (wid & 1) * 64;

  const f32x4 fz = {0.f,0.f,0.f,0.f};
  f32x4 acc[4][4];
  #pragma unroll
  for (int i=0;i<4;++i){
    #pragma unroll
    for (int j=0;j<4;++j) acc[i][j] = fz;
  }

  int sc = wid * 2;   // wave's two 1KB chunks per 8KB region

  auto stage = [&](int p, int kt){
    int kb = kt * 32;
    #pragma unroll
    for (int c=0;c<2;++c){
      int s   = (sc + c)*64 + lane;       // slot: row = s>>2, colgrp = s&3
      int row = s >> 2;
      int cg8 = (s & 3) * 8;
      size_t ga = (size_t)(m0 + row)*1024 + kb + cg8;
      size_t gb = (size_t)(n0 + row)*1024 + kb + cg8;
      int lo = (sc + c)*512;              // u16 offset of this 1KB chunk
      gload_lds16(&xh[ga], &sA[p][0][lo]);
      gload_lds16(&xl[ga], &sA[p][1][lo]);
      gload_lds16(&Bh[gb], &sB[p][0][lo]);
      gload_lds16(&Bl[gb], &sB[p][1][lo]);
    }
  };

  stage(0, 0);
  __syncthreads();                        // prologue drain

  for (int kt = 0; kt < 32; ++kt){
    int cur = kt & 1;
    if (kt + 1 < 32) stage(cur ^ 1, kt + 1);   // async; drains at end barrier

    bf16x8 ah[4], al[4];
    #pragma unroll
    for (int mf=0; mf<4; ++mf){
      int off = (wm + mf*16 + r)*32 + quad*8;
      ah[mf] = *(const bf16x8*)&sA[cur][0][off];
      al[mf] = *(const bf16x8*)&sA[cur][1][off];
    }
    #pragma unroll
    for (int nf=0; nf<4; ++nf){
      int off = (wn + nf*16 + r)*32 + quad*8;
      bf16x8 bh8 = *(const bf16x8*)&sB[cur][0][off];
      bf16x8 bl8 = *(const bf16x8*)&sB[cur][1][off];
      #pragma unroll
      for (int mf=0; mf<4; ++mf){
        acc[mf][nf] = mfma16(ah[mf], bh8, acc[mf][nf]);
        acc[mf][nf] = mfma16(al[mf], bh8, acc[mf][nf]);
        acc[mf][nf] = mfma16(ah[mf], bl8, acc[mf][nf]);
      }
    }
    __syncthreads();   // stage(kt+1) landed (hidden behind compute);
                       // cur reads done before next overwrite
  }

  float vals[4][4][4];
  #pragma unroll
  for (int mf=0;mf<4;++mf){
    #pragma unroll
    for (int nf=0;nf<4;++nf){
      float bb = bias[n0 + wn + nf*16 + r];
      #pragma unroll
      for (int e=0;e<4;++e) vals[mf][nf][e] = acc[mf][nf][e] + bb;
    }
  }
  if (zi < 2){
    #pragma unroll
    for (int mf=0;mf<4;++mf){
      #pragma unroll
      for (int e=0;e<4;++e){
        int t = t0 + wm + mf*16 + quad*4 + e;
        #pragma unroll
        for (int nf=0;nf<2;++nf){
          int d = nf*16 + r;
          float c1 = rcos[t*64 + d],      s1 = rsin[t*64 + d];
          float c2 = rcos[t*64 + d + 32], s2 = rsin[t*64 + d + 32];
          float x1 = vals[mf][nf][e], x2 = vals[mf][nf+2][e];
          vals[mf][nf][e]   = x1*c1 - x2*s1;
          vals[mf][nf+2][e] = x2*c2 + x1*s2;
        }
      }
    }
  }
  #pragma unroll
  for (int mf=0;mf<4;++mf){
    #pragma unroll
    for (int e=0;e<4;++e){
      int t = t0 + wm + mf*16 + quad*4 + e;
      float msk = (t < cnt) ? 1.f : 0.f;
      #pragma unroll
      for (int nf=0;nf<4;++nf){
        int gc = n0 + wn + nf*16 + r;
        int head = gc >> 6, d = gc & 63;
        float v = vals[mf][nf][e] * msk;
        u16 hh, ll; split2(v, hh, ll);
        size_t bh8t = (size_t)(b*16 + head)*8;
        if (zi == 0){
          size_t o = ((size_t)(b*16 + head)*512 + t)*64 + d;
          qh[o] = hh; ql[o] = ll;
        } else if (zi == 1){
          size_t o = ((bh8t + (t>>6))*64 + (t&63))*64 + (d ^ ((t&7)<<3));
          knt[o] = hh;
        } else {
          size_t o = ((bh8t + (t>>6))*64 + d)*64 + ((t&63) ^ ((d&7)<<3));
          vnt[o] = hh;
        }
      }
    }
  }
}

// ------- past K/V -> bf16, masked, swizzled; V transposed per tile -------
// ckh: [bh][3584 j][64 d], d swizzled by j&7 (row-major == tiled)
// cvt: [bh][56 t][64 d][64 j], j swizzled by d&7  (V^T)
__global__ __launch_bounds__(256) void k_conv(
    const float* __restrict__ pk, const float* __restrict__ pv,
    const int* __restrict__ plen,
    u16* __restrict__ ckh, u16* __restrict__ cvt)
{
  int t = blockIdx.x, h = blockIdx.y, b = blockIdx.z;
  int Lp = min(max(plen[b], 0), NP);
  int jend = min(((Lp + 63) >> 6) << 6, NP);
  if (t*64 >= jend) return;
  int tid = threadIdx.x;
  int bh = b*16 + h;
  int row = tid >> 2, cg = (tid & 3) * 16;
  int jj = t*64 + row;
  size_t src = ((size_t)bh*NP + jj)*64;

  __shared__ float tl[64][65];

  float4 kv4[4], vv4[4];
  #pragma unroll
  for (int i=0;i<4;++i){
    kv4[i] = *(const float4*)&pk[src + cg + i*4];
    vv4[i] = *(const float4*)&pv[src + cg + i*4];
  }
  if (jj >= Lp){
    float4 z4 = {0.f,0.f,0.f,0.f};
    #pragma unroll
    for (int i=0;i<4;++i){ kv4[i]=z4; vv4[i]=z4; }
  }
  // K store (swizzled)
  size_t kdst = ((size_t)bh*NP + jj)*64;
  #pragma unroll
  for (int i=0;i<4;++i){
    int c4 = cg + i*4;
    *(ushort4*)&ckh[kdst + (c4 ^ ((jj&7)<<3))] = cvt4(kv4[i]);
  }
  // V to LDS (row-major f32), then read transposed
  #pragma unroll
  for (int i=0;i<4;++i){
    tl[row][cg+i*4+0] = vv4[i].x;
    tl[row][cg+i*4+1] = vv4[i].y;
    tl[row][cg+i*4+2] = vv4[i].z;
    tl[row][cg+i*4+3] = vv4[i].w;
  }
  __syncthreads();
  int d = tid >> 2, jg = (tid & 3) * 16;
  size_t vdst = (((size_t)bh*56 + t)*64 + d)*64;
  #pragma unroll
  for (int i=0;i<4;++i){
    int j4 = jg + i*4;
    ushort4 hv;
    hv.x = bf16rn(tl[j4+0][d]);
    hv.y = bf16rn(tl[j4+1][d]);
    hv.z = bf16rn(tl[j4+2][d]);
    hv.w = bf16rn(tl[j4+3][d]);
    *(ushort4*)&cvt[vdst + (j4 ^ ((d&7)<<3))] = hv;
  }
}

// ---------------- flash attention, split-K, fixed-max softmax ----------------
__global__ __launch_bounds__(256,3) void k_attn(
    const u16* __restrict__ qh_, const u16* __restrict__ ql_,
    const u16* __restrict__ knt, const u16* __restrict__ vnt,
    const u16* __restrict__ ckh, const u16* __restrict__ cvt,
    const int* __restrict__ plen, const int* __restrict__ cnts,
    int S, float* __restrict__ pl, float* __restrict__ pO)
{
  int qt = blockIdx.x, h = blockIdx.y;
  int zb = blockIdx.z;
  int b = zb / S, s = zb - b * S;
  int cnt = cnts[b];
  int q0 = qt * 128;
  if (q0 >= cnt) return;
  int Lp = min(max(plen[b], 0), NP);
  int TL = Lp + cnt;
  int Ln = max(0, TL - NP);
  int jend = min(((Lp + 63) >> 6) << 6, NP);
  int minTLP = min(TL, NP);
  int Zar = max(0, minTLP - jend);
  int npast = jend >> 6, nnew = (Ln + 63) >> 6;
  int Tt = npast + nnew;
  int TLu = min(TL, jend) + Ln;          // unified valid-key prefix length
  int qsp = (Tt + S - 1) / S;
  int it0 = s * qsp, it1 = min(Tt, it0 + qsp);
  bool hasZ = (s == 0 && Zar > 0);
  if (it0 >= it1 && !hasZ) return;

  __shared__ __align__(16) u16 sK [2][4096];
  __shared__ __align__(16) u16 sVT[2][4096];
  __shared__ __align__(16) u16 sP [4][2048];

  int tid = threadIdx.x, lane = tid & 63, wid = tid >> 6;
  int r = lane & 15, quad = lane >> 4;
  int wm0 = wid * 32;
  int bh = b*16 + h;

  bf16x8 Qh[2][2], Ql[2][2];
  size_t qbase = ((size_t)bh*512 + q0 + wm0) * 64;
  #pragma unroll
  for (int mf=0;mf<2;++mf){
    #pragma unroll
    for (int ks=0;ks<2;++ks){
      size_t o = qbase + (size_t)(mf*16 + r)*64 + ks*32 + quad*8;
      Qh[mf][ks] = *(const bf16x8*)&qh_[o];
      Ql[mf][ks] = *(const bf16x8*)&ql_[o];
    }
  }

  const f32x4 fz = {0.f,0.f,0.f,0.f};
  f32x4 O[2][4];
  float lsum[2][4];
  #pragma unroll
  for (int mf=0;mf<2;++mf){
    #pragma unroll
    for (int e=0;e<4;++e) lsum[mf][e] = 0.f;
    #pragma unroll
    for (int nf=0;nf<4;++nf) O[mf][nf] = fz;
  }

  const float kscale = 0.125f * 1.44269504088896340736f;  // scale*log2(e)
  int ub = wid * 512;   // per-wave staging base (u16 elems)

  auto stage = [&](int pp, int it){
    const u16* ks; const u16* vs;
    if (it < npast){
      ks = ckh + ((size_t)bh*NP + (size_t)it*64)*64;
      vs = cvt + ((size_t)bh*56 + it)*4096;
    } else {
      ks = knt + ((size_t)bh*8 + (it - npast))*4096;
      vs = vnt + ((size_t)bh*8 + (it - npast))*4096;
    }
    gload_lds16(ks + ub + lane*8,        &sK [pp][ub]);
    gload_lds16(ks + ub + 2048 + lane*8, &sK [pp][ub + 2048]);
    gload_lds16(vs + ub + lane*8,        &sVT[pp][ub]);
    gload_lds16(vs + ub + 2048 + lane*8, &sVT[pp][ub + 2048]);
  };

  int p = 0;
  if (it0 < it1) stage(0, it0);
  __syncthreads();

  for (int it = it0; it < it1; ++it){
    if (it + 1 < it1) stage(p^1, it + 1);   // async, drains at barrier [B]

    // QK^T from sK[p] (swizzled reads, conflict-free)
    f32x4 Sc[2][4];
    #pragma unroll
    for (int mf=0;mf<2;++mf){
      #pragma unroll
      for (int jf=0;jf<4;++jf) Sc[mf][jf] = fz;
    }
    #pragma unroll
    for (int ks=0;ks<2;++ks){
      #pragma unroll
      for (int jf=0;jf<4;++jf){
        int jr = jf*16 + r;
        int off = jr*64 + ((ks*32 + quad*8) ^ ((jr&7)<<3));
        bf16x8 kbh = *(const bf16x8*)&sK[p][off];
        #pragma unroll
        for (int mf=0;mf<2;++mf){
          Sc[mf][jf] = mfma16(Qh[mf][ks], kbh, Sc[mf][jf]);
          Sc[mf][jf] = mfma16(Ql[mf][ks], kbh, Sc[mf][jf]);
        }
      }
    }

    // fixed-max softmax: p = exp2(s*kscale - 4); sP swizzled by (row>>2)&7
    int jlim = TLu - it*64;
    #pragma unroll
    for (int mf=0;mf<2;++mf){
      #pragma unroll
      for (int e=0;e<4;++e){
        int row = mf*16 + quad*4 + e;
        int sw = ((row>>2)&7) << 3;
        float ls = 0.f;
        #pragma unroll
        for (int jf=0;jf<4;++jf){
          float sv = Sc[mf][jf][e] * kscale - 4.0f;
          sv = (jf*16 + r < jlim) ? sv : -3.0e38f;
          float pj = exp2f(sv);
          ls += pj;
          __bf16 pb = (__bf16)pj;
          sP[wid][row*64 + ((jf*16 + r) ^ sw)] = __builtin_bit_cast(u16, pb);
        }
        lsum[mf][e] += ls;
      }
    }
    __syncthreads();   // [B] stage(p^1) landed (drain hidden behind QK+softmax);
                       //     sP visible; all QK reads of sK[p] done

    // O += P V from sVT[p]
    #pragma unroll
    for (int ks=0;ks<2;++ks){
      bf16x8 pah[2];
      #pragma unroll
      for (int mf=0;mf<2;++mf){
        int row = mf*16 + r;
        pah[mf] = *(const bf16x8*)&sP[wid][row*64 + ((ks*32 + quad*8) ^ (((row>>2)&7)<<3))];
      }
      #pragma unroll
      for (int nf=0;nf<4;++nf){
        int d = nf*16 + r;
        bf16x8 vbh = *(const bf16x8*)&sVT[p][d*64 + ((ks*32 + quad*8) ^ ((d&7)<<3))];
        #pragma unroll
        for (int mf=0;mf<2;++mf){
          O[mf][nf] = mfma16(pah[mf], vbh, O[mf][nf]);
        }
      }
    }
    __syncthreads();   // [C] PV reads done before next iter's stage overwrites
    p ^= 1;
  }

  // write partials: l (row sum over lanes) + un-normalized O (fp32)
  int pidx = ((b*16 + h)*4 + qt)*S + s;
  float* plr = pl + (size_t)pidx*128;
  float* po  = pO + (size_t)pidx*8192;
  float zadd = (s == 0) ? (float)Zar * 0.0625f : 0.f;
  #pragma unroll
  for (int mf=0;mf<2;++mf){
    #pragma unroll
    for (int e=0;e<4;++e){
      int row = wm0 + mf*16 + quad*4 + e;
      float l = lsum[mf][e];
      l += __shfl_xor(l, 1);
      l += __shfl_xor(l, 2);
      l += __shfl_xor(l, 4);
      l += __shfl_xor(l, 8);
      if (r == 0) plr[row] = l + zadd;
      #pragma unroll
      for (int nf=0;nf<4;++nf) po[row*64 + nf*16 + r] = O[mf][nf][e];
    }
  }
}

// ---------------- combine split-K partials (plain sum) ----------------
__global__ __launch_bounds__(256) void k_reduce(
    const float* __restrict__ pl, const float* __restrict__ pO,
    const int* __restrict__ plen, const int* __restrict__ cnts,
    int S, u16* __restrict__ aoh, u16* __restrict__ aol)
{
  int qt = blockIdx.x, h = blockIdx.y, b = blockIdx.z;
  int cnt = cnts[b]; int q0 = qt*128;
  if (q0 >= cnt) return;
  int Lp = min(max(plen[b], 0), NP);
  int TL = Lp + cnt;
  int Ln = max(0, TL - NP);
  int jend = min(((Lp + 63) >> 6) << 6, NP);
  int minTLP = min(TL, NP);
  int Zar = max(0, minTLP - jend);
  int npast = jend >> 6, nnew = (Ln + 63) >> 6;
  int Tt = npast + nnew;
  int qsp = (Tt + S - 1) / S;

  int tid = threadIdx.x;
  int row = tid >> 1, c0 = (tid & 1) * 32;
  int base = ((b*16 + h)*4 + qt)*S;

  float L = 0.f;
  float acc[32];
  #pragma unroll
  for (int i=0;i<32;++i) acc[i] = 0.f;
  for (int s2=0;s2<S;++s2){
    bool act = (s2*qsp < Tt) || (s2 == 0 && Zar > 0);
    if (!act) continue;
    L += pl[(size_t)(base+s2)*128 + row];
    const float4* po = (const float4*)(pO + (size_t)(base+s2)*8192 + row*64 + c0);
    #pragma unroll
    for (int i=0;i<8;++i){
      float4 v = po[i];
      acc[4*i+0] += v.x; acc[4*i+1] += v.y; acc[4*i+2] += v.z; acc[4*i+3] += v.w;
    }
  }
  float inv = 1.f / L;
  size_t o = ((size_t)b*512 + q0 + row)*1024 + h*64 + c0;
  #pragma unroll
  for (int i=0;i<8;++i){
    ushort4 hv, lv;
    u16 hh, ll;
    split2(acc[4*i+0]*inv, hh, ll); hv.x=hh; lv.x=ll;
    split2(acc[4*i+1]*inv, hh, ll); hv.y=hh; lv.y=ll;
    split2(acc[4*i+2]*inv, hh, ll); hv.z=hh; lv.z=ll;
    split2(acc[4*i+3]*inv, hh, ll); hv.w=hh; lv.w=ll;
    *(ushort4*)&aoh[o + 4*i] = hv;
    *(ushort4*)&aol[o + 4*i] = lv;
  }
}

// ---------------- output projection GEMM + bias + mask ----------------
__global__ __launch_bounds__(256,2) void k_oproj(
    const u16* __restrict__ ah_, const u16* __restrict__ al_,
    const u16* __restrict__ Wth, const u16* __restrict__ Wtl,
    const float* __restrict__ bo, const int* __restrict__ cnts,
    float* __restrict__ out)
{
  int bx = blockIdx.x, by = blockIdx.y;
  int n0 = ((bx & 3)*2 + (by & 1)) * 128;
  int m0 = ((bx >> 2)*16 + (by >> 1)) * 128;
  int b = m0 >> 9, t0 = m0 & 511;
  int cnt = cnts[b];
  int tid = threadIdx.x;
  if (t0 >= cnt){
    float4 z4 = {0.f,0.f,0.f,0.f};
    #pragma unroll
    for (int i=0;i<16;++i){
      int v = tid + i*256;
      int row = v >> 5, c4 = (v & 31) * 4;
      *(float4*)&out[(size_t)(m0+row)*1024 + n0 + c4] = z4;
    }
    return;
  }
  const u16* Bh = Wth + 3ull*1024*1024;
  const u16* Bl = Wtl + 3ull*1024*1024;

  __shared__ __align__(16) u16 sA[2][2][4096];
  __shared__ __align__(16) u16 sB[2][2][4096];

  int lane = tid & 63, wid = tid >> 6;
  int r = lane & 15, quad = lane >> 4;
  int wm = (wid >> 1) * 64, wn = (wid & 1) * 64;

  const f32x4 fz = {0.f,0.f,0.f,0.f};
  f32x4 acc[4][4];
  #pragma unroll
  for (int i=0;i<4;++i){
    #pragma unroll
    for (int j=0;j<4;++j) acc[i][j] = fz;
  }

  int sc = wid * 2;

  auto stage = [&](int p, int kt){
    int kb = kt * 32;
    #pragma unroll
    for (int c=0;c<2;++c){
      int s   = (sc + c)*64 + lane;
      int row = s >> 2;
      int cg8 = (s & 3) * 8;
      size_t ga = (size_t)(m0 + row)*1024 + kb + cg8;
      size_t gb = (size_t)(n0 + row)*1024 + kb + cg8;
      int lo = (sc + c)*512;
      gload_lds16(&ah_[ga], &sA[p][0][lo]);
      gload_lds16(&al_[ga], &sA[p][1][lo]);
      gload_lds16(&Bh[gb],  &sB[p][0][lo]);
      gload_lds16(&Bl[gb],  &sB[p][1][lo]);
    }
  };

  stage(0, 0);
  __syncthreads();

  for (int kt = 0; kt < 32; ++kt){
    int cur = kt & 1;
    if (kt + 1 < 32) stage(cur ^ 1, kt + 1);

    bf16x8 ah8[4], al8[4];
    #pragma unroll
    for (int mf=0; mf<4; ++mf){
      int off = (wm + mf*16 + r)*32 + quad*8;
      ah8[mf] = *(const bf16x8*)&sA[cur][0][off];
      al8[mf] = *(const bf16x8*)&sA[cur][1][off];
    }
    #pragma unroll
    for (int nf=0; nf<4; ++nf){
      int off = (wn + nf*16 + r)*32 + quad*8;
      bf16x8 bh8 = *(const bf16x8*)&sB[cur][0][off];
      bf16x8 bl8 = *(const bf16x8*)&sB[cur][1][off];
      #pragma unroll
      for (int mf=0; mf<4; ++mf){
        acc[mf][nf] = mfma16(ah8[mf], bh8, acc[mf][nf]);
        acc[mf][nf] = mfma16(al8[mf], bh8, acc[mf][nf]);
        acc[mf][nf] = mfma16(ah8[mf], bl8, acc[mf][nf]);
      }
    }
    __syncthreads();
  }

  #pragma unroll
  for (int mf=0;mf<4;++mf){
    #pragma unroll
    for (int e=0;e<4;++e){
      int t = t0 + wm + mf*16 + quad*4 + e;
      float msk = (t < cnt) ? 1.f : 0.f;
      int row = m0 + wm + mf*16 + quad*4 + e;
      #pragma unroll
      for (int nf=0;nf<4;++nf){
        int gc = n0 + wn + nf*16 + r;
        out[(size_t)row*1024 + gc] = (acc[mf][nf][e] + bo[gc]) * msk;
      }
    }
  }
}

extern "C" void kernel_launch(void* const* d_in, const int* in_sizes, int n_in,
                              void* d_out, int out_size, void* d_ws, size_t ws_size,
                              hipStream_t stream) {
  (void)in_sizes; (void)n_in; (void)out_size;
  const float* x    = (const float*)d_in[0];
  const float* rcos = (const float*)d_in[1];
  const float* rsin = (const float*)d_in[2];
  const float* pk   = (const float*)d_in[3];
  const float* pv   = (const float*)d_in[4];
  const int*   plen = (const int*)d_in[5];
  const int*   cnts = (const int*)d_in[7];
  const float* Wq = (const float*)d_in[8];
  const float* bq = (const float*)d_in[9];
  const float* Wk = (const float*)d_in[10];
  const float* bk = (const float*)d_in[11];
  const float* Wv = (const float*)d_in[12];
  const float* bv = (const float*)d_in[13];
  const float* Wo = (const float*)d_in[14];
  const float* bo = (const float*)d_in[15];
  float* out = (float*)d_out;

  char* w = (char*)d_ws;
  const size_t MB = 1ull << 20;
  u16* Wth = (u16*)(w + 0*MB);        // 8 MB (4 matrices, hi)
  u16* Wtl = (u16*)(w + 8*MB);        // 8 MB (lo)
  u16* qh  = (u16*)(w + 16*MB);       // 8 MB
  u16* ql  = (u16*)(w + 24*MB);       // 8 MB
  u16* knt = (u16*)(w + 32*MB);       // 8 MB  new-K tiled/swizzled
  u16* vnt = (u16*)(w + 40*MB);       // 8 MB  new-V^T tiled/swizzled
  u16* ckh = (u16*)(w + 48*MB);       // 56 MB past-K bf16 swizzled
  u16* xh  = (u16*)(w + 48*MB);       //  (alias: x hi, dead before k_conv)
  u16* xl  = (u16*)(w + 56*MB);       //  (alias: x lo)
  u16* cvt = (u16*)(w + 104*MB);      // 56 MB past-V^T bf16 tiled/swizzled
  float* pl = (float*)(w + 160*MB);   // 2 MB
  float* pO = (float*)(w + 162*MB);   // 16 MB per split
  u16* aoh = xh;                      // attn-out hi (ckh dead after k_attn)
  u16* aol = xl;

  int S = (int)((ws_size - 162*MB) / (16*MB));
  if (S > 8) S = 8;
  if (S < 1) S = 1;

  k_split_x<<<dim3(4096), dim3(256), 0, stream>>>(x, xh, xl);
  k_wsplit<<<dim3(16,16,4), dim3(256), 0, stream>>>(Wq, Wk, Wv, Wo, Wth, Wtl);
  k_qkv<<<dim3(8,32,3), dim3(256), 0, stream>>>(xh, xl, Wth, Wtl, bq, bk, bv,
                                                rcos, rsin, cnts,
                                                qh, ql, knt, vnt);
  k_conv<<<dim3(56,16,8), dim3(256), 0, stream>>>(pk, pv, plen, ckh, cvt);
  k_attn<<<dim3(4,16,8*S), dim3(256), 0, stream>>>(qh, ql, knt, vnt, ckh, cvt,
                                                   plen, cnts, S, pl, pO);
  k_reduce<<<dim3(4,16,8), dim3(256), 0, stream>>>(pl, pO, plen, cnts, S, aoh, aol);
  k_oproj<<<dim3(8,32), dim3(256), 0, stream>>>(aoh, aol, Wth, Wtl, bo, cnts, out);
}